// Round 20
// baseline (153.869 us; speedup 1.0000x reference)
//
#include <hip/hip_runtime.h>
#include <math.h>

#define NN 8192
#define DD 128
#define THRESH 0.15f

typedef __attribute__((ext_vector_type(8))) short short8;
typedef __attribute__((ext_vector_type(4))) float f32x4;
typedef __attribute__((ext_vector_type(4))) unsigned int u32x4;
typedef __attribute__((address_space(1))) const void g_void;
typedef __attribute__((address_space(3))) void l_void;

__device__ __forceinline__ unsigned umax2(unsigned a, unsigned b) { return a > b ? a : b; }
__device__ __forceinline__ unsigned umin2(unsigned a, unsigned b) { return a < b ? a : b; }
#define CEX(A, B) { unsigned _h = umax2(A, B); B = umin2(A, B); A = _h; }

__device__ __forceinline__ unsigned short f2bf(float f) {
    unsigned int u = __float_as_uint(f);
    return (unsigned short)((u + 0x7fffu + ((u >> 16) & 1u)) >> 16);
}

__device__ __forceinline__ void gl2lds16(const void* g, void* l) {
    __builtin_amdgcn_global_load_lds((g_void*)g, (l_void*)l, 16, 0, 0);
}

// branch-free insert of key k into sorted-desc m[0..7]
__device__ __forceinline__ void ins8k(unsigned* m, unsigned k) {
#pragma unroll
    for (int s = 0; s < 8; ++s) { unsigned h = umax2(m[s], k); k = umin2(m[s], k); m[s] = h; }
}

// merge my sorted-8 with lane^d's sorted-8, keep top-8 (bitonic)
__device__ __forceinline__ void merge8(unsigned* m, int d) {
    unsigned z[8];
#pragma unroll
    for (int s = 0; s < 8; ++s) z[s] = umax2(m[s], __shfl_xor(m[7 - s], d));
    CEX(z[0],z[4]); CEX(z[1],z[5]); CEX(z[2],z[6]); CEX(z[3],z[7]);
    CEX(z[0],z[2]); CEX(z[1],z[3]); CEX(z[4],z[6]); CEX(z[5],z[7]);
    CEX(z[0],z[1]); CEX(z[2],z[3]); CEX(z[4],z[5]); CEX(z[6],z[7]);
#pragma unroll
    for (int s = 0; s < 8; ++s) m[s] = z[s];
}

// sorted-desc top-4 insert (tie: smaller index). Only on wave-uniform data.
__device__ __forceinline__ void ins4(float v, int j, float* tv, int* ti) {
    bool b3 = (v > tv[3]) | ((v == tv[3]) & (j < ti[3]));
    if (b3) {
        bool b0 = (v > tv[0]) | ((v == tv[0]) & (j < ti[0]));
        bool b1 = (v > tv[1]) | ((v == tv[1]) & (j < ti[1]));
        bool b2 = (v > tv[2]) | ((v == tv[2]) & (j < ti[2]));
        if (b0)      { tv[3]=tv[2];ti[3]=ti[2]; tv[2]=tv[1];ti[2]=ti[1]; tv[1]=tv[0];ti[1]=ti[0]; tv[0]=v;ti[0]=j; }
        else if (b1) { tv[3]=tv[2];ti[3]=ti[2]; tv[2]=tv[1];ti[2]=ti[1]; tv[1]=v;ti[1]=j; }
        else if (b2) { tv[3]=tv[2];ti[3]=ti[2]; tv[2]=v;ti[2]=j; }
        else         { tv[3]=v;ti[3]=j; }
    }
}

// ---- K1: normalize rows, emit bf16 x-hat in MFMA-fragment-major layout ----
__global__ __launch_bounds__(256) void norm_frag(const float* __restrict__ x,
                                                 u32x4* __restrict__ F) {
    const int t = threadIdx.x;
    const int c = blockIdx.x;
    const int row = t >> 4;
    const int seg = t & 15;
    const float* xr = x + (size_t)(c * 16 + row) * DD + seg * 8;
    float4 v0 = reinterpret_cast<const float4*>(xr)[0];
    float4 v1 = reinterpret_cast<const float4*>(xr)[1];
    float ss = v0.x*v0.x + v0.y*v0.y + v0.z*v0.z + v0.w*v0.w
             + v1.x*v1.x + v1.y*v1.y + v1.z*v1.z + v1.w*v1.w;
#pragma unroll
    for (int d = 1; d < 16; d <<= 1) ss += __shfl_xor(ss, d);
    const float inv = 1.0f / fmaxf(sqrtf(ss), 1e-12f);
    u32x4 p;
    p.x = ((unsigned)f2bf(v0.y*inv) << 16) | f2bf(v0.x*inv);
    p.y = ((unsigned)f2bf(v0.w*inv) << 16) | f2bf(v0.z*inv);
    p.z = ((unsigned)f2bf(v1.y*inv) << 16) | f2bf(v1.x*inv);
    p.w = ((unsigned)f2bf(v1.w*inv) << 16) | f2bf(v1.z*inv);
    const int kc = seg >> 2, r = seg & 3;
    F[(size_t)(c * 4 + kc) * 64 + r * 16 + row] = p;
}

// ---- K2: LDS-staged fused sweep. Block = 128 rows (8 waves x 16) x 1/4 of
// candidate groups. Chunks of 8 groups (32 KB) double-buffered via async
// global_load_lds; ds_read_b128 consumption; interleaved zero-fill;
// per-wave top-8 keys written directly (no cross-wave merge). ----
__global__ __launch_bounds__(512, 2) void fused_build(const char* __restrict__ Fb,
                                                      unsigned* __restrict__ keys,
                                                      f32x4* __restrict__ out) {
    __shared__ __align__(16) char buf[2][32768];
    const int bid = blockIdx.x;
    const int rb = bid >> 2, cb = bid & 3;
    const int t = threadIdx.x, lane = t & 63, w = t >> 6;  // 8 waves
    const int l15 = lane & 15, r = lane >> 4;
    const int i0 = rb * 128;

    // rf: this wave's 16-row fragment set (row-group rb*8 + w)
    const short8* F = reinterpret_cast<const short8*>(Fb);
    const int rg = rb * 8 + w;
    short8 rf[4];
#pragma unroll
    for (int kc = 0; kc < 4; ++kc)
        rf[kc] = F[(size_t)(rg * 4 + kc) * 64 + lane];

    unsigned m[8];
#pragma unroll
    for (int s = 0; s < 8; ++s) m[s] = 0u;

    const size_t cbase = (size_t)cb * 128 * 4096;          // block's group bytes
    const int loff = w * 1024 + lane * 16;                 // per-lane src offset
    const int ldst = w * 1024;                             // wave-uniform LDS base

    // prologue: stage chunk 0 into buf 0
#pragma unroll
    for (int k = 0; k < 4; ++k)
        gl2lds16(Fb + cbase + k * 8192 + loff, &buf[0][0] + ldst + k * 8192);
    __syncthreads();

    const f32x4 z = {0.f, 0.f, 0.f, 0.f};
    const size_t fb = (size_t)bid * 131072 + t;            // block's 2 MB fill share

    for (int c = 0; c < 16; ++c) {
        const int cur = c & 1;
        if (c + 1 < 16) {                                  // async stage next chunk
            const char* src = Fb + cbase + (size_t)(c + 1) * 32768 + loff;
            char* dst = &buf[cur ^ 1][0] + ldst;
#pragma unroll
            for (int k = 0; k < 4; ++k)
                gl2lds16(src + k * 8192, dst + k * 8192);
        }
        const int gbase = cb * 128 + c * 8;
#pragma unroll
        for (int g = 0; g < 8; ++g) {
            const char* bp = &buf[cur][0] + g * 4096 + lane * 16;
            const short8 a0 = *reinterpret_cast<const short8*>(bp);
            const short8 a1 = *reinterpret_cast<const short8*>(bp + 1024);
            const short8 a2 = *reinterpret_cast<const short8*>(bp + 2048);
            const short8 a3 = *reinterpret_cast<const short8*>(bp + 3072);
            f32x4 acc = {0.f, 0.f, 0.f, 0.f};
            acc = __builtin_amdgcn_mfma_f32_16x16x32_bf16(a0, rf[0], acc, 0, 0, 0);
            acc = __builtin_amdgcn_mfma_f32_16x16x32_bf16(a1, rf[1], acc, 0, 0, 0);
            acc = __builtin_amdgcn_mfma_f32_16x16x32_bf16(a2, rf[2], acc, 0, 0, 0);
            acc = __builtin_amdgcn_mfma_f32_16x16x32_bf16(a3, rf[3], acc, 0, 0, 0);

            // interleaved zero-fill: 2 coalesced f32x4 stores per group
            out[fb + (size_t)c * 8192 + g * 1024]       = z;
            out[fb + (size_t)c * 8192 + g * 1024 + 512] = z;

            const unsigned jb = (unsigned)((gbase + g) * 16 + r * 4);
            ins8k(m, (__float_as_uint(fmaxf(acc[0], 0.f)) & 0xFFFFE000u) | (jb + 0));
            ins8k(m, (__float_as_uint(fmaxf(acc[1], 0.f)) & 0xFFFFE000u) | (jb + 1));
            ins8k(m, (__float_as_uint(fmaxf(acc[2], 0.f)) & 0xFFFFE000u) | (jb + 2));
            ins8k(m, (__float_as_uint(fmaxf(acc[3], 0.f)) & 0xFFFFE000u) | (jb + 3));
        }
        __syncthreads();    // drains stage (vmcnt) + readies buffer swap
    }

    // merge the 4 r-lanes sharing each row; write this wave's rows directly
    merge8(m, 16); merge8(m, 32);
    if (r == 0) {
        const size_t row = (size_t)(i0 + w * 16 + l15);
#pragma unroll
        for (int s = 0; s < 8; ++s)
            keys[row * 32 + cb * 8 + s] = m[s];
    }
}

// ---- K3: exact fp32 rerank of each row's 32 keys (4 parts x 8), scatter ----
__global__ __launch_bounds__(256) void rerank(const float* __restrict__ x,
                                              const unsigned* __restrict__ keys,
                                              float* __restrict__ adj,
                                              float* __restrict__ ew) {
    const int t = threadIdx.x, lane = t & 63, w = t >> 6;
    const int i = blockIdx.x * 4 + w;
    const float2 a = reinterpret_cast<const float2*>(x + (size_t)i * DD)[lane];
    float ss = a.x * a.x + a.y * a.y;
#pragma unroll
    for (int d = 1; d < 64; d <<= 1) ss += __shfl_xor(ss, d);
    const float ni = fmaxf(sqrtf(ss), 1e-12f);
    float tv[4]; int ti[4];
#pragma unroll
    for (int s = 0; s < 4; ++s) { tv[s] = -1e30f; ti[s] = 0x7fffffff; }
#pragma unroll
    for (int c = 0; c < 32; ++c) {
        const unsigned key = keys[(size_t)i * 32 + c];
        const int j = (int)(key & 0x1FFFu);
        if (key == 0u || j == i) continue;               // wave-uniform branch
        const float2 b = reinterpret_cast<const float2*>(x + (size_t)j * DD)[lane];
        float dp = a.x * b.x + a.y * b.y;
        float sb = b.x * b.x + b.y * b.y;
#pragma unroll
        for (int d = 1; d < 64; d <<= 1) {
            dp += __shfl_xor(dp, d);
            sb += __shfl_xor(sb, d);
        }
        const float sim = dp / (ni * fmaxf(sqrtf(sb), 1e-12f));
        ins4(sim, j, tv, ti);
    }
    if (lane == 0) {
#pragma unroll
        for (int s = 0; s < 4; ++s)
            if (tv[s] > THRESH) {
                adj[(size_t)i * NN + ti[s]] = 1.0f;
                ew [(size_t)i * NN + ti[s]] = tv[s];
            }
    }
}

extern "C" void kernel_launch(void* const* d_in, const int* in_sizes, int n_in,
                              void* d_out, int out_size, void* d_ws, size_t ws_size,
                              hipStream_t stream) {
    const float* x = (const float*)d_in[0];
    u32x4* F = (u32x4*)d_ws;                                // 2 MB fragment-major x-hat
    unsigned* keys = (unsigned*)((char*)d_ws + (2u << 20)); // 1 MB top-8 keys x 4 parts
    float* adj = (float*)d_out;
    float* ew  = adj + (size_t)NN * NN;

    hipLaunchKernelGGL(norm_frag,   dim3(NN / 16), dim3(256), 0, stream, x, F);
    hipLaunchKernelGGL(fused_build, dim3(256),     dim3(512), 0, stream,
                       (const char*)F, keys, (f32x4*)d_out);
    hipLaunchKernelGGL(rerank,      dim3(NN / 4),  dim3(256), 0, stream, x, keys, adj, ew);
}

// Round 21
// 139.891 us; speedup vs baseline: 1.0999x; 1.0999x over previous
//
#include <hip/hip_runtime.h>
#include <math.h>

#define NN 8192
#define DD 128
#define THRESH 0.15f

typedef __attribute__((ext_vector_type(8))) short short8;
typedef __attribute__((ext_vector_type(4))) float f32x4;
typedef __attribute__((ext_vector_type(4))) unsigned int u32x4;

__device__ __forceinline__ unsigned umax2(unsigned a, unsigned b) { return a > b ? a : b; }
__device__ __forceinline__ unsigned umin2(unsigned a, unsigned b) { return a < b ? a : b; }
#define CEX(A, B) { unsigned _h = umax2(A, B); B = umin2(A, B); A = _h; }

__device__ __forceinline__ unsigned short f2bf(float f) {
    unsigned int u = __float_as_uint(f);
    return (unsigned short)((u + 0x7fffu + ((u >> 16) & 1u)) >> 16);
}

// branch-free insert of key k into sorted-desc m[0..4] (m[5..7] stay 0-pad)
__device__ __forceinline__ void ins5k(unsigned* m, unsigned k) {
#pragma unroll
    for (int s = 0; s < 5; ++s) { unsigned h = umax2(m[s], k); k = umin2(m[s], k); m[s] = h; }
}

// merge my sorted-8 with lane^d's sorted-8, keep top-8 (bitonic)
__device__ __forceinline__ void merge8(unsigned* m, int d) {
    unsigned z[8];
#pragma unroll
    for (int s = 0; s < 8; ++s) z[s] = umax2(m[s], __shfl_xor(m[7 - s], d));
    CEX(z[0],z[4]); CEX(z[1],z[5]); CEX(z[2],z[6]); CEX(z[3],z[7]);
    CEX(z[0],z[2]); CEX(z[1],z[3]); CEX(z[4],z[6]); CEX(z[5],z[7]);
    CEX(z[0],z[1]); CEX(z[2],z[3]); CEX(z[4],z[5]); CEX(z[6],z[7]);
#pragma unroll
    for (int s = 0; s < 8; ++s) m[s] = z[s];
}

// merge my sorted-16 with lane^d's sorted-16, keep top-16 (bitonic)
__device__ __forceinline__ void merge16(unsigned* K, int d) {
    unsigned z[16];
#pragma unroll
    for (int s = 0; s < 16; ++s) z[s] = umax2(K[s], __shfl_xor(K[15 - s], d));
#pragma unroll
    for (int s = 0; s < 8; ++s) CEX(z[s], z[s + 8]);
    CEX(z[0],z[4]);  CEX(z[1],z[5]);  CEX(z[2],z[6]);  CEX(z[3],z[7]);
    CEX(z[8],z[12]); CEX(z[9],z[13]); CEX(z[10],z[14]); CEX(z[11],z[15]);
    CEX(z[0],z[2]);  CEX(z[1],z[3]);  CEX(z[4],z[6]);  CEX(z[5],z[7]);
    CEX(z[8],z[10]); CEX(z[9],z[11]); CEX(z[12],z[14]); CEX(z[13],z[15]);
#pragma unroll
    for (int s = 0; s < 16; s += 2) CEX(z[s], z[s + 1]);
#pragma unroll
    for (int s = 0; s < 16; ++s) K[s] = z[s];
}

// sorted-desc top-4 insert (tie: smaller index). Only on wave-uniform data.
__device__ __forceinline__ void ins4(float v, int j, float* tv, int* ti) {
    bool b3 = (v > tv[3]) | ((v == tv[3]) & (j < ti[3]));
    if (b3) {
        bool b0 = (v > tv[0]) | ((v == tv[0]) & (j < ti[0]));
        bool b1 = (v > tv[1]) | ((v == tv[1]) & (j < ti[1]));
        bool b2 = (v > tv[2]) | ((v == tv[2]) & (j < ti[2]));
        if (b0)      { tv[3]=tv[2];ti[3]=ti[2]; tv[2]=tv[1];ti[2]=ti[1]; tv[1]=tv[0];ti[1]=ti[0]; tv[0]=v;ti[0]=j; }
        else if (b1) { tv[3]=tv[2];ti[3]=ti[2]; tv[2]=tv[1];ti[2]=ti[1]; tv[1]=v;ti[1]=j; }
        else if (b2) { tv[3]=tv[2];ti[3]=ti[2]; tv[2]=v;ti[2]=j; }
        else         { tv[3]=v;ti[3]=j; }
    }
}

// ---- K1: normalize rows, emit bf16 x-hat in MFMA-fragment-major layout ----
__global__ __launch_bounds__(256) void norm_frag(const float* __restrict__ x,
                                                 u32x4* __restrict__ F) {
    const int t = threadIdx.x;
    const int c = blockIdx.x;
    const int row = t >> 4;
    const int seg = t & 15;
    const float* xr = x + (size_t)(c * 16 + row) * DD + seg * 8;
    float4 v0 = reinterpret_cast<const float4*>(xr)[0];
    float4 v1 = reinterpret_cast<const float4*>(xr)[1];
    float ss = v0.x*v0.x + v0.y*v0.y + v0.z*v0.z + v0.w*v0.w
             + v1.x*v1.x + v1.y*v1.y + v1.z*v1.z + v1.w*v1.w;
#pragma unroll
    for (int d = 1; d < 16; d <<= 1) ss += __shfl_xor(ss, d);
    const float inv = 1.0f / fmaxf(sqrtf(ss), 1e-12f);
    u32x4 p;
    p.x = ((unsigned)f2bf(v0.y*inv) << 16) | f2bf(v0.x*inv);
    p.y = ((unsigned)f2bf(v0.w*inv) << 16) | f2bf(v0.z*inv);
    p.z = ((unsigned)f2bf(v1.y*inv) << 16) | f2bf(v1.x*inv);
    p.w = ((unsigned)f2bf(v1.w*inv) << 16) | f2bf(v1.z*inv);
    const int kc = seg >> 2, r = seg & 3;
    F[(size_t)(c * 4 + kc) * 64 + r * 16 + row] = p;
}

// ---- K2: fused sweep (R19 structure: 8-load batches, 2 row-sets, stagger,
// interleaved zero-fill) with 5-deep per-lane insertion (ins5k). ----
__global__ __launch_bounds__(512, 4) void fused_build(const short8* __restrict__ F,
                                                      unsigned* __restrict__ keys,
                                                      f32x4* __restrict__ out) {
    __shared__ unsigned wvk[8][32][8];                     // 8 KB
    const int bid = blockIdx.x;
    const int t = threadIdx.x, lane = t & 63, w = t >> 6;  // 8 waves
    const int i0 = bid * 32;
    const int l15 = lane & 15, r = lane >> 4;
    const int g0 = bid * 2;

    short8 rf0[4], rf1[4];
#pragma unroll
    for (int kc = 0; kc < 4; ++kc) {
        rf0[kc] = F[(size_t)(g0 * 4 + kc) * 64 + lane];
        rf1[kc] = F[(size_t)((g0 + 1) * 4 + kc) * 64 + lane];
    }

    unsigned m0[8], m1[8];                                 // [0..4] live, [5..7] pad
#pragma unroll
    for (int s = 0; s < 8; ++s) { m0[s] = 0u; m1[s] = 0u; }

    const f32x4 z = {0.f, 0.f, 0.f, 0.f};
    const size_t fb = (size_t)bid * 131072 + t;   // block's 2 MB fill share (f32x4)
    const int rot = (bid * 2) & 63;               // stagger: decorrelate L2 access

    for (int it = 0; it < 32; ++it) {
        const int k1 = (it * 2 + rot) & 63;
        const int k2 = (it * 2 + 1 + rot) & 63;
        const int g1 = k1 * 8 + w;
        const int g2 = k2 * 8 + w;
        // one 8-load batch (one latency exposure for 16 MFMAs / 16 values)
        const short8 a0 = F[(size_t)(g1 * 4 + 0) * 64 + lane];
        const short8 a1 = F[(size_t)(g1 * 4 + 1) * 64 + lane];
        const short8 a2 = F[(size_t)(g1 * 4 + 2) * 64 + lane];
        const short8 a3 = F[(size_t)(g1 * 4 + 3) * 64 + lane];
        const short8 a4 = F[(size_t)(g2 * 4 + 0) * 64 + lane];
        const short8 a5 = F[(size_t)(g2 * 4 + 1) * 64 + lane];
        const short8 a6 = F[(size_t)(g2 * 4 + 2) * 64 + lane];
        const short8 a7 = F[(size_t)(g2 * 4 + 3) * 64 + lane];

        f32x4 acc00 = {0.f,0.f,0.f,0.f}, acc01 = {0.f,0.f,0.f,0.f};
        f32x4 acc10 = {0.f,0.f,0.f,0.f}, acc11 = {0.f,0.f,0.f,0.f};
        acc00 = __builtin_amdgcn_mfma_f32_16x16x32_bf16(a0, rf0[0], acc00, 0, 0, 0);
        acc01 = __builtin_amdgcn_mfma_f32_16x16x32_bf16(a0, rf1[0], acc01, 0, 0, 0);
        acc10 = __builtin_amdgcn_mfma_f32_16x16x32_bf16(a4, rf0[0], acc10, 0, 0, 0);
        acc11 = __builtin_amdgcn_mfma_f32_16x16x32_bf16(a4, rf1[0], acc11, 0, 0, 0);
        acc00 = __builtin_amdgcn_mfma_f32_16x16x32_bf16(a1, rf0[1], acc00, 0, 0, 0);
        acc01 = __builtin_amdgcn_mfma_f32_16x16x32_bf16(a1, rf1[1], acc01, 0, 0, 0);
        acc10 = __builtin_amdgcn_mfma_f32_16x16x32_bf16(a5, rf0[1], acc10, 0, 0, 0);
        acc11 = __builtin_amdgcn_mfma_f32_16x16x32_bf16(a5, rf1[1], acc11, 0, 0, 0);
        acc00 = __builtin_amdgcn_mfma_f32_16x16x32_bf16(a2, rf0[2], acc00, 0, 0, 0);
        acc01 = __builtin_amdgcn_mfma_f32_16x16x32_bf16(a2, rf1[2], acc01, 0, 0, 0);
        acc10 = __builtin_amdgcn_mfma_f32_16x16x32_bf16(a6, rf0[2], acc10, 0, 0, 0);
        acc11 = __builtin_amdgcn_mfma_f32_16x16x32_bf16(a6, rf1[2], acc11, 0, 0, 0);
        acc00 = __builtin_amdgcn_mfma_f32_16x16x32_bf16(a3, rf0[3], acc00, 0, 0, 0);
        acc01 = __builtin_amdgcn_mfma_f32_16x16x32_bf16(a3, rf1[3], acc01, 0, 0, 0);
        acc10 = __builtin_amdgcn_mfma_f32_16x16x32_bf16(a7, rf0[3], acc10, 0, 0, 0);
        acc11 = __builtin_amdgcn_mfma_f32_16x16x32_bf16(a7, rf1[3], acc11, 0, 0, 0);

        // interleaved zero-fill: 8 coalesced f32x4 stores (64 KB/block/iter)
#pragma unroll
        for (int s = 0; s < 8; ++s)
            out[fb + (size_t)it * 4096 + s * 512] = z;

        const unsigned jb1 = (unsigned)(g1 * 16 + r * 4);
        const unsigned jb2 = (unsigned)(g2 * 16 + r * 4);
#pragma unroll
        for (int q = 0; q < 4; ++q) {
            ins5k(m0, (__float_as_uint(fmaxf(acc00[q], 0.f)) & 0xFFFFE000u) | (jb1 + q));
            ins5k(m0, (__float_as_uint(fmaxf(acc10[q], 0.f)) & 0xFFFFE000u) | (jb2 + q));
            ins5k(m1, (__float_as_uint(fmaxf(acc01[q], 0.f)) & 0xFFFFE000u) | (jb1 + q));
            ins5k(m1, (__float_as_uint(fmaxf(acc11[q], 0.f)) & 0xFFFFE000u) | (jb2 + q));
        }
    }

    // merge the 4 r-lanes sharing each row -> per-wave row top-8 (of 4x5 union)
    merge8(m0, 16); merge8(m0, 32);
    merge8(m1, 16); merge8(m1, 32);
    if (r == 0) {
#pragma unroll
        for (int s = 0; s < 8; ++s) {
            wvk[w][l15][s]      = m0[s];
            wvk[w][l15 + 16][s] = m1[s];
        }
    }
    __syncthreads();

    // ---- final: wave w merges rows 4w..4w+3 -> top-16, writes keys ----
    for (int rr = 0; rr < 4; ++rr) {
        const int lrow = w * 4 + rr;
        const unsigned e0 = wvk[lane >> 3][lrow][lane & 7];   // 64 keys, 1/lane
        unsigned K[16];
        K[0] = e0;
#pragma unroll
        for (int s = 1; s < 16; ++s) K[s] = 0u;
        merge16(K, 1); merge16(K, 2); merge16(K, 4);
        merge16(K, 8); merge16(K, 16); merge16(K, 32);
        if (lane == 0) {
#pragma unroll
            for (int s = 0; s < 16; ++s)
                keys[(size_t)(i0 + lrow) * 16 + s] = K[s];
        }
    }
}

// ---- K3: exact fp32 rerank of each row's 16 keys, scatter adj/ew ----
__global__ __launch_bounds__(256) void rerank(const float* __restrict__ x,
                                              const unsigned* __restrict__ keys,
                                              float* __restrict__ adj,
                                              float* __restrict__ ew) {
    const int t = threadIdx.x, lane = t & 63, w = t >> 6;
    const int i = blockIdx.x * 4 + w;
    const float2 a = reinterpret_cast<const float2*>(x + (size_t)i * DD)[lane];
    float ss = a.x * a.x + a.y * a.y;
#pragma unroll
    for (int d = 1; d < 64; d <<= 1) ss += __shfl_xor(ss, d);
    const float ni = fmaxf(sqrtf(ss), 1e-12f);
    float tv[4]; int ti[4];
#pragma unroll
    for (int s = 0; s < 4; ++s) { tv[s] = -1e30f; ti[s] = 0x7fffffff; }
#pragma unroll
    for (int c = 0; c < 16; ++c) {
        const unsigned key = keys[(size_t)i * 16 + c];
        const int j = (int)(key & 0x1FFFu);
        if (key == 0u || j == i) continue;               // wave-uniform branch
        const float2 b = reinterpret_cast<const float2*>(x + (size_t)j * DD)[lane];
        float dp = a.x * b.x + a.y * b.y;
        float sb = b.x * b.x + b.y * b.y;
#pragma unroll
        for (int d = 1; d < 64; d <<= 1) {
            dp += __shfl_xor(dp, d);
            sb += __shfl_xor(sb, d);
        }
        const float sim = dp / (ni * fmaxf(sqrtf(sb), 1e-12f));
        ins4(sim, j, tv, ti);
    }
    if (lane == 0) {
#pragma unroll
        for (int s = 0; s < 4; ++s)
            if (tv[s] > THRESH) {
                adj[(size_t)i * NN + ti[s]] = 1.0f;
                ew [(size_t)i * NN + ti[s]] = tv[s];
            }
    }
}

extern "C" void kernel_launch(void* const* d_in, const int* in_sizes, int n_in,
                              void* d_out, int out_size, void* d_ws, size_t ws_size,
                              hipStream_t stream) {
    const float* x = (const float*)d_in[0];
    u32x4* F = (u32x4*)d_ws;                                // 2 MB fragment-major x-hat
    unsigned* keys = (unsigned*)((char*)d_ws + (2u << 20)); // 512 KB top-16 keys
    float* adj = (float*)d_out;
    float* ew  = adj + (size_t)NN * NN;

    hipLaunchKernelGGL(norm_frag,   dim3(NN / 16), dim3(256), 0, stream, x, F);
    hipLaunchKernelGGL(fused_build, dim3(256),     dim3(512), 0, stream,
                       (const short8*)F, keys, (f32x4*)d_out);
    hipLaunchKernelGGL(rerank,      dim3(NN / 4),  dim3(256), 0, stream, x, keys, adj, ew);
}